// Round 7
// baseline (766.517 us; speedup 1.0000x reference)
//
#include <hip/hip_runtime.h>
#include <hip/hip_bf16.h>

#define N_NODES 50000
#define N_EDGES 800000
#define N_REL 8
#define N_BASES 16
#define D 128
#define NCB 196                       // coarse buckets of 256 dsts
#define NSEG (N_NODES * N_REL)        // 400000 (dst,rel) segments
#define NFB 1563                      // fused blocks: ceil(50000/32)
#define STG 1536                      // staged edges per chunk

typedef __attribute__((ext_vector_type(8))) short bf16x8;
typedef __attribute__((ext_vector_type(4))) float f32x4;

__device__ inline unsigned short f2bf(float f) {
    unsigned int x = __float_as_uint(f);
    unsigned int r = x + 0x7FFFu + ((x >> 16) & 1u);
    return (unsigned short)(r >> 16);
}
__device__ inline float bf2f(unsigned short u) {
    return __uint_as_float(((unsigned int)u) << 16);
}
__device__ inline unsigned int cvtpk(float lo, float hi) {
    unsigned int r;
    asm("v_cvt_pk_bf16_f32 %0, %1, %2" : "=v"(r) : "v"(lo), "v"(hi));
    return r;
}

// ---------------------------------------------------------------------------
// WbT[r][o][i] = bf16( (r<8 ? sum_b coeff[r,b]*bases[b] : self_loop)[i][o] )
__global__ __launch_bounds__(256) void k_makeW(const float* __restrict__ coeff,
                                               const float* __restrict__ bases,
                                               const float* __restrict__ self_loop,
                                               unsigned short* __restrict__ WbT) {
    const int r = blockIdx.x;  // 0..8
    __shared__ unsigned short tile[128][130];
    if (r < 8) {
        float c[16];
#pragma unroll
        for (int b = 0; b < 16; ++b) c[b] = coeff[r * 16 + b];
        for (int i = threadIdx.x; i < 16384; i += 256) {
            float s = 0.f;
#pragma unroll
            for (int b = 0; b < 16; ++b) s += c[b] * bases[b * 16384 + i];
            tile[i >> 7][i & 127] = f2bf(s);
        }
    } else {
        for (int i = threadIdx.x; i < 16384; i += 256)
            tile[i >> 7][i & 127] = f2bf(self_loop[i]);
    }
    __syncthreads();
    for (int i = threadIdx.x; i < 16384; i += 256) {
        int o = i >> 7, k = i & 127;
        WbT[r * 16384 + o * 128 + k] = tile[k][o];   // [o][k]
    }
}

// ---------------------------------------------------------------------------
// xb = bf16(x)
__global__ __launch_bounds__(256) void k_cvtx(const float* __restrict__ x,
                                              unsigned short* __restrict__ xb) {
    int i = blockIdx.x * 256 + threadIdx.x;   // grid exact: 3125*256 = 800000
    const float4* xp = (const float4*)x;
    float4 a = xp[i * 2], b = xp[i * 2 + 1];
    int4 o;
    o.x = (int)f2bf(a.x) | ((int)f2bf(a.y) << 16);
    o.y = (int)f2bf(a.z) | ((int)f2bf(a.w) << 16);
    o.z = (int)f2bf(b.x) | ((int)f2bf(b.y) << 16);
    o.w = (int)f2bf(b.z) | ((int)f2bf(b.w) << 16);
    ((int4*)xb)[i] = o;
}

// ---------------------------------------------------------------------------
// coarse histogram of dst>>8
__global__ __launch_bounds__(256) void k_histA(const int* __restrict__ ei,
                                               int* __restrict__ ccnt) {
    __shared__ int h[256];
    int t = threadIdx.x;
    h[t] = 0;
    __syncthreads();
    int idx = blockIdx.x * 1024 + t * 4;
    if (idx < N_EDGES) {
        int4 d = *(const int4*)&ei[N_EDGES + idx];
        atomicAdd(&h[d.x >> 8], 1);
        atomicAdd(&h[d.y >> 8], 1);
        atomicAdd(&h[d.z >> 8], 1);
        atomicAdd(&h[d.w >> 8], 1);
    }
    __syncthreads();
    if (t < NCB && h[t]) atomicAdd(&ccnt[t], h[t]);
}

// ---------------------------------------------------------------------------
// exclusive scan of ccnt[196] -> coff[197], gcur; pad roff2 tail with total
__global__ __launch_bounds__(256) void k_scanA1(const int* __restrict__ ccnt,
                                                int* __restrict__ coff,
                                                int* __restrict__ gcur,
                                                int* __restrict__ roff2) {
    int t = threadIdx.x;
    int v = (t < NCB) ? ccnt[t] : 0;
    int lane = t & 63, wv = t >> 6;
    int inc = v;
#pragma unroll
    for (int off = 1; off < 64; off <<= 1) {
        int y = __shfl_up(inc, off);
        if (lane >= off) inc += y;
    }
    __shared__ int ws4[4];
    __shared__ int tot;
    if (lane == 63) ws4[wv] = inc;
    __syncthreads();
    int wb = 0;
    for (int i = 0; i < wv; ++i) wb += ws4[i];
    int ex = wb + inc - v;
    if (t < NCB) { coff[t] = ex; gcur[t] = ex; }
    if (t == NCB - 1) { coff[NCB] = ex + v; tot = ex + v; }
    __syncthreads();
    // pad: segments for dst in [50000, 50016) must read empty
    for (int i = t; i < 192; i += 256) roff2[NSEG + i] = tot;
}

// ---------------------------------------------------------------------------
// bucket edges into coarse segments; rec = src | rel<<16 | (dst&255)<<19
#define ACHUNK 2048
__global__ __launch_bounds__(256) void k_bucketA(const int* __restrict__ ei,
                                                 const int* __restrict__ et,
                                                 int* __restrict__ gcur,
                                                 unsigned int* __restrict__ recA) {
    __shared__ int lcnt[NCB], lbase[NCB];
    const int base = blockIdx.x * ACHUNK;
    const int t = threadIdx.x;
    if (t < NCB) lcnt[t] = 0;
    __syncthreads();
    unsigned int rec[8];
    int mb[8];
#pragma unroll
    for (int i = 0; i < 8; ++i) {
        int e = base + t + i * 256;
        if (e < N_EDGES) {
            int src = ei[e];
            int dst = ei[N_EDGES + e];
            int r = et[e];
            rec[i] = (unsigned)src | ((unsigned)r << 16) | ((unsigned)(dst & 255) << 19);
            mb[i] = dst >> 8;
            atomicAdd(&lcnt[mb[i]], 1);
        } else mb[i] = -1;
    }
    __syncthreads();
    if (t < NCB) lbase[t] = lcnt[t] ? atomicAdd(&gcur[t], lcnt[t]) : 0;
    __syncthreads();
    if (t < NCB) lcnt[t] = 0;
    __syncthreads();
#pragma unroll
    for (int i = 0; i < 8; ++i) {
        if (mb[i] < 0) continue;
        int pos = lbase[mb[i]] + atomicAdd(&lcnt[mb[i]], 1);
        recA[pos] = rec[i];
    }
}

// ---------------------------------------------------------------------------
// per coarse bucket: (dst,rel)-sorted csr32 + roff2 (all LDS atomics)
// csr32 = src | (seg-local-within-32dst-block)<<16  (seglocal = idx2 & 255)
__global__ __launch_bounds__(256) void k_buildC(const unsigned int* __restrict__ recA,
                                                const int* __restrict__ coff,
                                                int* __restrict__ roff2,
                                                unsigned int* __restrict__ csr32) {
    const int b = blockIdx.x, t = threadIdx.x;
    const int s0 = coff[b], s1 = coff[b + 1];
    __shared__ int h2[2048];    // (dst&255)*8 + rel
    __shared__ int cur2[2048];
    __shared__ int ws4[4];
    for (int i = t; i < 2048; i += 256) h2[i] = 0;
    __syncthreads();
    for (int i = s0 + t; i < s1; i += 256) {
        unsigned int p = recA[i];
        atomicAdd(&h2[((p >> 19) & 255) * 8 + ((p >> 16) & 7)], 1);
    }
    __syncthreads();
    // exclusive scan over 2048 entries, thread t owns [t*8, t*8+8)
    int pre[8], sum = 0;
#pragma unroll
    for (int j = 0; j < 8; ++j) { pre[j] = sum; sum += h2[t * 8 + j]; }
    int lane = t & 63, wv = t >> 6;
    int inc = sum;
#pragma unroll
    for (int off = 1; off < 64; off <<= 1) {
        int y = __shfl_up(inc, off);
        if (lane >= off) inc += y;
    }
    if (lane == 63) ws4[wv] = inc;
    __syncthreads();
    int wb = 0;
    for (int i = 0; i < wv; ++i) wb += ws4[i];
    int ex = wb + inc - sum;
    int dst = (b << 8) + t;
#pragma unroll
    for (int j = 0; j < 8; ++j) cur2[t * 8 + j] = ex + pre[j];
    if (dst < N_NODES) {
#pragma unroll
        for (int j = 0; j < 8; ++j) roff2[dst * 8 + j] = s0 + ex + pre[j];
    }
    __syncthreads();
    for (int i = s0 + t; i < s1; i += 256) {
        unsigned int p = recA[i];
        int idx2 = ((p >> 19) & 255) * 8 + ((p >> 16) & 7);
        int pos = s0 + atomicAdd(&cur2[idx2], 1);
        csr32[pos] = (p & 0xFFFFu) | ((unsigned)(idx2 & 255) << 16);
    }
}

// ---------------------------------------------------------------------------
// FUSED: 32 dsts/block. Phase 1: edge-parallel ds_add_f32 aggregation of
// dinv-scaled x[src] rows into fp32 LDS (swizzled). Phase 2: 9-panel MFMA.
__global__ __launch_bounds__(512, 1) void k_fused(const unsigned short* __restrict__ xb,
                                                  const unsigned short* __restrict__ WbT,
                                                  const unsigned int* __restrict__ csr32,
                                                  const int* __restrict__ roff2,
                                                  float* __restrict__ out) {
    __shared__ __attribute__((aligned(16))) float accS[256 * 128];  // 128 KB
    __shared__ unsigned int sE[STG];                                 // 6 KB
    __shared__ int roff_s[257];
    __shared__ float sdinv[256];
    const int g = blockIdx.x;
    const int g32 = g * 32;
    const int t = threadIdx.x;
    const int wv = t >> 6, lane = t & 63;

    if (t < 257) roff_s[t] = roff2[g * 256 + t];
    // zero accS (float4 stores)
    {
        float4 z = make_float4(0.f, 0.f, 0.f, 0.f);
        for (int i = t; i < 256 * 128 / 4; i += 512) ((float4*)accS)[i] = z;
    }
    __syncthreads();
    if (t < 256) {
        int n = roff_s[t + 1] - roff_s[t];
        sdinv[t] = 1.0f / fmaxf((float)n, 1.0f);
    }
    const int e0 = roff_s[0];
    const int nE = roff_s[256] - e0;
    __syncthreads();

    // ---- phase 1: edge-parallel aggregation
    const int l2 = lane << 1;
    for (int chunk = 0; chunk < nE; chunk += STG) {
        int m = min(nE - chunk, STG);
        for (int i = t; i < m; i += 512) sE[i] = csr32[e0 + chunk + i];
        __syncthreads();
        int per = (m + 7) >> 3;
        int lo = wv * per;
        int hi = min(lo + per, m);
        int j = lo;
        for (; j + 8 <= hi; j += 8) {
            unsigned rec[8], v[8];
            float dv[8];
            int base[8];
#pragma unroll
            for (int k = 0; k < 8; ++k) rec[k] = sE[j + k];
#pragma unroll
            for (int k = 0; k < 8; ++k) {
                int src = rec[k] & 0xFFFF;
                int s = rec[k] >> 16;
                dv[k] = sdinv[s];
                base[k] = s * 128 + (l2 ^ (((s >> 3) & 7) << 2));
                v[k] = *(const unsigned*)&xb[src * D + l2];
            }
#pragma unroll
            for (int k = 0; k < 8; ++k) {
                atomicAdd(&accS[base[k]],     __uint_as_float(v[k] << 16) * dv[k]);
                atomicAdd(&accS[base[k] + 1], __uint_as_float(v[k] & 0xFFFF0000u) * dv[k]);
            }
        }
        for (; j < hi; ++j) {
            unsigned rec = sE[j];
            int src = rec & 0xFFFF;
            int s = rec >> 16;
            float dv = sdinv[s];
            int base = s * 128 + (l2 ^ (((s >> 3) & 7) << 2));
            unsigned v = *(const unsigned*)&xb[src * D + l2];
            atomicAdd(&accS[base],     __uint_as_float(v << 16) * dv);
            atomicAdd(&accS[base + 1], __uint_as_float(v & 0xFFFF0000u) * dv);
        }
        __syncthreads();
    }

    // ---- phase 2: MFMA. wave wv -> cols [wv*16, wv*16+16)
    const int lr = lane & 15, lg = lane >> 4;
    const int colb = wv << 4;
    const int h2 = (lr & 7) << 2;
    f32x4 acc0 = {0.f, 0.f, 0.f, 0.f}, acc1 = {0.f, 0.f, 0.f, 0.f};
    union U8 { unsigned int u[4]; bf16x8 v; };
#pragma unroll
    for (int rel = 0; rel < 8; ++rel) {
        const unsigned short* Wp = WbT + rel * 16384 + (colb + lr) * 128;
        const int sA = (lr * 8 + rel) * 128;
        const int sB = ((lr + 16) * 8 + rel) * 128;
#pragma unroll
        for (int kk = 0; kk < 4; ++kk) {
            bf16x8 bfr = *(const bf16x8*)&Wp[kk * 32 + lg * 8];
            int c = (kk * 32 + lg * 8) ^ h2;
            float4 A0 = *(const float4*)&accS[sA + c];
            float4 A1 = *(const float4*)&accS[sA + (c ^ 4)];
            float4 B0 = *(const float4*)&accS[sB + c];
            float4 B1 = *(const float4*)&accS[sB + (c ^ 4)];
            U8 ua, ub;
            ua.u[0] = cvtpk(A0.x, A0.y); ua.u[1] = cvtpk(A0.z, A0.w);
            ua.u[2] = cvtpk(A1.x, A1.y); ua.u[3] = cvtpk(A1.z, A1.w);
            ub.u[0] = cvtpk(B0.x, B0.y); ub.u[1] = cvtpk(B0.z, B0.w);
            ub.u[2] = cvtpk(B1.x, B1.y); ub.u[3] = cvtpk(B1.z, B1.w);
            acc0 = __builtin_amdgcn_mfma_f32_16x16x32_bf16(ua.v, bfr, acc0, 0, 0, 0);
            acc1 = __builtin_amdgcn_mfma_f32_16x16x32_bf16(ub.v, bfr, acc1, 0, 0, 0);
        }
    }
    {   // self-loop panel: A rows straight from xb
        const unsigned short* Wp = WbT + 8 * 16384 + (colb + lr) * 128;
        int r0 = min(g32 + lr, N_NODES - 1);
        int r1 = min(g32 + 16 + lr, N_NODES - 1);
#pragma unroll
        for (int kk = 0; kk < 4; ++kk) {
            bf16x8 bfr = *(const bf16x8*)&Wp[kk * 32 + lg * 8];
            bf16x8 a0 = *(const bf16x8*)&xb[(size_t)r0 * D + kk * 32 + lg * 8];
            bf16x8 a1 = *(const bf16x8*)&xb[(size_t)r1 * D + kk * 32 + lg * 8];
            acc0 = __builtin_amdgcn_mfma_f32_16x16x32_bf16(a0, bfr, acc0, 0, 0, 0);
            acc1 = __builtin_amdgcn_mfma_f32_16x16x32_bf16(a1, bfr, acc1, 0, 0, 0);
        }
    }
#pragma unroll
    for (int q = 0; q < 4; ++q) {
        int row = g32 + lg * 4 + q;
        if (row < N_NODES) out[(size_t)row * D + colb + lr] = acc0[q];
    }
#pragma unroll
    for (int q = 0; q < 4; ++q) {
        int row = g32 + 16 + lg * 4 + q;
        if (row < N_NODES) out[(size_t)row * D + colb + lr] = acc1[q];
    }
}

// ---------------------------------------------------------------------------
extern "C" void kernel_launch(void* const* d_in, const int* in_sizes, int n_in,
                              void* d_out, int out_size, void* d_ws, size_t ws_size,
                              hipStream_t stream) {
    const float* x         = (const float*)d_in[0];
    const float* bases     = (const float*)d_in[1];
    const float* coeff     = (const float*)d_in[2];
    const float* self_loop = (const float*)d_in[3];
    const int*   ei        = (const int*)d_in[4];
    const int*   et        = (const int*)d_in[5];
    float* out = (float*)d_out;

    char* ws = (char*)d_ws;
    size_t o = 0;
    auto alloc = [&](size_t bytes) { size_t r = o; o += (bytes + 255) & ~(size_t)255; return r; };
    size_t o_ccnt   = alloc(256 * 4);                        // zeroed
    size_t zero_end = o;
    size_t o_coff   = alloc((NCB + 1) * 4);
    size_t o_gcur   = alloc(NCB * 4);
    size_t o_recA   = alloc((size_t)N_EDGES * 4);
    size_t o_csr32  = alloc((size_t)N_EDGES * 4);
    size_t o_roff2  = alloc((size_t)(NSEG + 192) * 4);
    size_t o_WbT    = alloc((size_t)9 * 16384 * 2);
    size_t o_xb     = alloc((size_t)N_NODES * D * 2 + 4096);
    if (ws_size < o) return;

    int*            ccnt  = (int*)(ws + o_ccnt);
    int*            coff  = (int*)(ws + o_coff);
    int*            gcur  = (int*)(ws + o_gcur);
    unsigned int*   recA  = (unsigned int*)(ws + o_recA);
    unsigned int*   csr32 = (unsigned int*)(ws + o_csr32);
    int*            roff2 = (int*)(ws + o_roff2);
    unsigned short* WbT   = (unsigned short*)(ws + o_WbT);
    unsigned short* xb    = (unsigned short*)(ws + o_xb);

    hipMemsetAsync(ccnt, 0, zero_end, stream);

    k_makeW<<<9, 256, 0, stream>>>(coeff, bases, self_loop, WbT);
    k_cvtx<<<3125, 256, 0, stream>>>(x, xb);
    k_histA<<<(N_EDGES + 1023) / 1024, 256, 0, stream>>>(ei, ccnt);
    k_scanA1<<<1, 256, 0, stream>>>(ccnt, coff, gcur, roff2);
    k_bucketA<<<(N_EDGES + ACHUNK - 1) / ACHUNK, 256, 0, stream>>>(ei, et, gcur, recA);
    k_buildC<<<NCB, 256, 0, stream>>>(recA, coff, roff2, csr32);
    k_fused<<<NFB, 512, 0, stream>>>(xb, WbT, csr32, roff2, out);
}

// Round 8
// 151.101 us; speedup vs baseline: 5.0729x; 5.0729x over previous
//
#include <hip/hip_runtime.h>
#include <hip/hip_bf16.h>

#define N_NODES 50000
#define N_EDGES 800000
#define N_REL 8
#define N_BASES 16
#define D 128
#define NCB 196   // coarse buckets of 256 dsts

typedef __attribute__((ext_vector_type(8))) short bf16x8;
typedef __attribute__((ext_vector_type(4))) float f32x4;

__device__ inline unsigned short f2bf(float f) {
    unsigned int x = __float_as_uint(f);
    unsigned int r = x + 0x7FFFu + ((x >> 16) & 1u);
    return (unsigned short)(r >> 16);
}
__device__ inline float bf2f(unsigned short u) {
    return __uint_as_float(((unsigned int)u) << 16);
}

// ---------------------------------------------------------------------------
// WbT[r][o][i] = bf16( (r<8 ? sum_b coeff[r,b]*bases[b] : self_loop)[i][o] )
// grid (9, 8): r = x, o-slice of 16 = y
__global__ __launch_bounds__(256) void k_makeW(const float* __restrict__ coeff,
                                               const float* __restrict__ bases,
                                               const float* __restrict__ self_loop,
                                               unsigned short* __restrict__ WbT) {
    const int r = blockIdx.x, os = blockIdx.y;
    const int t = threadIdx.x;
    __shared__ unsigned short tile[128][17];   // [i][o_local]
    const int i = t >> 1, ob = (t & 1) * 8;
    const int gcol = os * 16 + ob;
    float s[8];
    if (r < 8) {
        float c[16];
#pragma unroll
        for (int b = 0; b < 16; ++b) c[b] = coeff[r * 16 + b];
#pragma unroll
        for (int j = 0; j < 8; ++j) s[j] = 0.f;
#pragma unroll
        for (int b = 0; b < 16; ++b) {
            const float* bp = bases + b * 16384 + i * 128 + gcol;
            float4 v0 = *(const float4*)bp;
            float4 v1 = *(const float4*)(bp + 4);
            s[0] += c[b] * v0.x; s[1] += c[b] * v0.y; s[2] += c[b] * v0.z; s[3] += c[b] * v0.w;
            s[4] += c[b] * v1.x; s[5] += c[b] * v1.y; s[6] += c[b] * v1.z; s[7] += c[b] * v1.w;
        }
    } else {
        const float* sp = self_loop + i * 128 + gcol;
        float4 v0 = *(const float4*)sp;
        float4 v1 = *(const float4*)(sp + 4);
        s[0] = v0.x; s[1] = v0.y; s[2] = v0.z; s[3] = v0.w;
        s[4] = v1.x; s[5] = v1.y; s[6] = v1.z; s[7] = v1.w;
    }
#pragma unroll
    for (int j = 0; j < 8; ++j) tile[i][ob + j] = f2bf(s[j]);
    __syncthreads();
    // write transposed: o row = t>>4, i-chunk = (t&15)*8
    const int o = t >> 4, ic = (t & 15) << 3;
    unsigned int pk[4];
#pragma unroll
    for (int j = 0; j < 4; ++j)
        pk[j] = (unsigned int)tile[ic + j * 2][o] | ((unsigned int)tile[ic + j * 2 + 1][o] << 16);
    *(int4*)&WbT[(size_t)r * 16384 + (os * 16 + o) * 128 + ic] = *(int4*)pk;
}

// ---------------------------------------------------------------------------
// xb = bf16(x)
__global__ __launch_bounds__(256) void k_cvtx(const float* __restrict__ x,
                                              unsigned short* __restrict__ xb) {
    int i = blockIdx.x * 256 + threadIdx.x;   // grid exact: 3125*256 = 800000
    const float4* xp = (const float4*)x;
    float4 a = xp[i * 2], b = xp[i * 2 + 1];
    int4 o;
    o.x = (int)f2bf(a.x) | ((int)f2bf(a.y) << 16);
    o.y = (int)f2bf(a.z) | ((int)f2bf(a.w) << 16);
    o.z = (int)f2bf(b.x) | ((int)f2bf(b.y) << 16);
    o.w = (int)f2bf(b.z) | ((int)f2bf(b.w) << 16);
    ((int4*)xb)[i] = o;
}

// ---------------------------------------------------------------------------
// coarse histogram of dst>>8
__global__ __launch_bounds__(256) void k_histA(const int* __restrict__ ei,
                                               int* __restrict__ ccnt) {
    __shared__ int h[256];
    int t = threadIdx.x;
    h[t] = 0;
    __syncthreads();
    int idx = blockIdx.x * 1024 + t * 4;
    if (idx < N_EDGES) {
        int4 d = *(const int4*)&ei[N_EDGES + idx];
        atomicAdd(&h[d.x >> 8], 1);
        atomicAdd(&h[d.y >> 8], 1);
        atomicAdd(&h[d.z >> 8], 1);
        atomicAdd(&h[d.w >> 8], 1);
    }
    __syncthreads();
    if (t < NCB && h[t]) atomicAdd(&ccnt[t], h[t]);
}

// ---------------------------------------------------------------------------
// exclusive scan of ccnt[196] -> coff[197], gcur; row_off[N] = total
__global__ __launch_bounds__(256) void k_scanA1(const int* __restrict__ ccnt,
                                                int* __restrict__ coff,
                                                int* __restrict__ gcur,
                                                int* __restrict__ row_off) {
    int t = threadIdx.x;
    int v = (t < NCB) ? ccnt[t] : 0;
    int lane = t & 63, wv = t >> 6;
    int inc = v;
#pragma unroll
    for (int off = 1; off < 64; off <<= 1) {
        int y = __shfl_up(inc, off);
        if (lane >= off) inc += y;
    }
    __shared__ int ws4[4];
    if (lane == 63) ws4[wv] = inc;
    __syncthreads();
    int wb = 0;
    for (int i = 0; i < wv; ++i) wb += ws4[i];
    int ex = wb + inc - v;
    if (t < NCB) { coff[t] = ex; gcur[t] = ex; }
    if (t == NCB - 1) { coff[NCB] = ex + v; row_off[N_NODES] = ex + v; }
}

// ---------------------------------------------------------------------------
// bucket edges into coarse segments; rec = src | rel<<16 | (dst&255)<<19
#define ACHUNK 2048
__global__ __launch_bounds__(256) void k_bucketA(const int* __restrict__ ei,
                                                 const int* __restrict__ et,
                                                 int* __restrict__ gcur,
                                                 unsigned int* __restrict__ recA) {
    __shared__ int lcnt[NCB], lbase[NCB];
    const int base = blockIdx.x * ACHUNK;
    const int t = threadIdx.x;
    if (t < NCB) lcnt[t] = 0;
    __syncthreads();
    unsigned int rec[8];
    int mb[8];
#pragma unroll
    for (int i = 0; i < 8; ++i) {
        int e = base + t + i * 256;
        if (e < N_EDGES) {
            int src = ei[e];
            int dst = ei[N_EDGES + e];
            int r = et[e];
            rec[i] = (unsigned)src | ((unsigned)r << 16) | ((unsigned)(dst & 255) << 19);
            mb[i] = dst >> 8;
            atomicAdd(&lcnt[mb[i]], 1);
        } else mb[i] = -1;
    }
    __syncthreads();
    if (t < NCB) lbase[t] = lcnt[t] ? atomicAdd(&gcur[t], lcnt[t]) : 0;
    __syncthreads();
    if (t < NCB) lcnt[t] = 0;
    __syncthreads();
#pragma unroll
    for (int i = 0; i < 8; ++i) {
        if (mb[i] < 0) continue;
        int pos = lbase[mb[i]] + atomicAdd(&lcnt[mb[i]], 1);
        recA[pos] = rec[i];
    }
}

// ---------------------------------------------------------------------------
// per coarse bucket: dst-sorted csr + row_off + dinv (all LDS atomics)
__global__ __launch_bounds__(256) void k_buildC(const unsigned int* __restrict__ recA,
                                                const int* __restrict__ coff,
                                                int* __restrict__ row_off,
                                                int* __restrict__ csr,
                                                float* __restrict__ dinv) {
    const int b = blockIdx.x, t = threadIdx.x;
    const int s0 = coff[b], s1 = coff[b + 1];
    __shared__ int h2[2048];   // (dst&255)*8 + rel
    __shared__ int cur[256];
    __shared__ int ws4[4];
    for (int i = t; i < 2048; i += 256) h2[i] = 0;
    __syncthreads();
    for (int i = s0 + t; i < s1; i += 256) {
        unsigned int p = recA[i];
        atomicAdd(&h2[((p >> 19) & 255) * 8 + ((p >> 16) & 7)], 1);
    }
    __syncthreads();
    int sum = 0;
#pragma unroll
    for (int r = 0; r < 8; ++r) sum += h2[t * 8 + r];
    int lane = t & 63, wv = t >> 6;
    int inc = sum;
#pragma unroll
    for (int off = 1; off < 64; off <<= 1) {
        int y = __shfl_up(inc, off);
        if (lane >= off) inc += y;
    }
    if (lane == 63) ws4[wv] = inc;
    __syncthreads();
    int wb = 0;
    for (int i = 0; i < wv; ++i) wb += ws4[i];
    int ex = wb + inc - sum;          // exclusive per-dst offset within bucket
    cur[t] = ex;
    int dst = (b << 8) + t;
    if (dst < N_NODES) row_off[dst] = s0 + ex;
    __syncthreads();
    for (int i = t; i < 2048; i += 256) {
        int d2 = (b << 8) + (i >> 3);
        if (d2 < N_NODES) dinv[(size_t)d2 * 8 + (i & 7)] = 1.0f / fmaxf((float)h2[i], 1.0f);
    }
    for (int i = s0 + t; i < s1; i += 256) {
        unsigned int p = recA[i];
        int pos = s0 + atomicAdd(&cur[(p >> 19) & 255], 1);
        csr[pos] = (int)(p & 0x7FFFF);   // src | rel<<16
    }
}

// ---------------------------------------------------------------------------
// per 128-row tile: stage A once, loop 9 panels. Panels 0-7 -> bf16 xW via
// LDS-staged coalesced dwordx4 stores; panel 8 (self) -> fp32 out.
__global__ __launch_bounds__(512) void k_mm_big(const unsigned short* __restrict__ xb,
                                                const unsigned short* __restrict__ WbT,
                                                unsigned short* __restrict__ xW,
                                                float* __restrict__ out, int M) {
    __shared__ unsigned short As[128][136];
    __shared__ unsigned short Bs[128][136];
    const int rb = blockIdx.x * 128;
    const int t = threadIdx.x;

    // stage A: 128x128 bf16, once
#pragma unroll
    for (int i = 0; i < 4; ++i) {
        int f = t + i * 512;
        int row = f >> 4, c8 = (f & 15) << 3;
        int gr = rb + row;
        int4 v = make_int4(0, 0, 0, 0);
        if (gr < M) v = *(const int4*)&xb[(size_t)gr * D + c8];
        *(int4*)&As[row][c8] = v;
    }

    const int w = t >> 6, lane = t & 63;
    const int rh = (w >> 2) * 64, cq = (w & 3) * 32;
    const int lr = lane & 15, lg = lane >> 4;

    for (int p = 0; p < 9; ++p) {
        __syncthreads();   // As ready (p=0) / Bs copy-out done (p>0)
        const unsigned short* Bsrc = WbT + p * 16384;
#pragma unroll
        for (int i = 0; i < 4; ++i) {
            int f = t + i * 512;
            int row = f >> 4, c8 = (f & 15) << 3;
            *(int4*)&Bs[row][c8] = *(const int4*)&Bsrc[row * 128 + c8];
        }
        __syncthreads();

        f32x4 acc[4][2] = {};
#pragma unroll
        for (int kk = 0; kk < 4; ++kk) {
            int ko = kk * 32 + lg * 8;
            bf16x8 a[4], b[2];
#pragma unroll
            for (int m = 0; m < 4; ++m) a[m] = *(const bf16x8*)&As[rh + m * 16 + lr][ko];
#pragma unroll
            for (int n = 0; n < 2; ++n) b[n] = *(const bf16x8*)&Bs[cq + n * 16 + lr][ko];
#pragma unroll
            for (int m = 0; m < 4; ++m)
#pragma unroll
                for (int n = 0; n < 2; ++n)
                    acc[m][n] = __builtin_amdgcn_mfma_f32_16x16x32_bf16(a[m], b[n], acc[m][n], 0, 0, 0);
        }

        if (p < 8) {
            __syncthreads();   // all waves done reading Bs
#pragma unroll
            for (int m = 0; m < 4; ++m)
#pragma unroll
                for (int n = 0; n < 2; ++n)
#pragma unroll
                    for (int q = 0; q < 4; ++q)
                        Bs[rh + m * 16 + lg * 4 + q][cq + n * 16 + lr] = f2bf(acc[m][n][q]);
            __syncthreads();
#pragma unroll
            for (int i = 0; i < 4; ++i) {
                int f = t + i * 512;
                int row = f >> 4, c8 = (f & 15) << 3;
                int gr = rb + row;
                if (gr < M) *(int4*)&xW[(size_t)gr * 1024 + p * 128 + c8] = *(const int4*)&Bs[row][c8];
            }
        } else {
#pragma unroll
            for (int m = 0; m < 4; ++m)
#pragma unroll
                for (int n = 0; n < 2; ++n)
#pragma unroll
                    for (int q = 0; q < 4; ++q) {
                        int grow = rb + rh + m * 16 + lg * 4 + q;
                        int col = cq + n * 16 + lr;
                        if (grow < M) out[(size_t)grow * 128 + col] = acc[m][n][q];
                    }
        }
    }
}

// ---------------------------------------------------------------------------
// gather: 4 edge-groups x 32 lanes x 4 bf16 (uint2 loads), LDS reduce
__global__ __launch_bounds__(128) void k_gather(const unsigned short* __restrict__ xWall,
                                                const int* __restrict__ csr,
                                                const int* __restrict__ row_off,
                                                const float* __restrict__ dinv,
                                                float* __restrict__ out) {
    const int dst = blockIdx.x;
    const int t = threadIdx.x;
    const int s0 = row_off[dst], s1 = row_off[dst + 1];
    const int n = s1 - s0;
    if (n <= 0) return;
    __shared__ float sdinv[N_REL];
    __shared__ int epack[128];
    __shared__ float sacc[512];
    if (t < N_REL) sdinv[t] = dinv[(size_t)dst * 8 + t];
    const int g = t >> 5, l = t & 31;
    float4 acc = make_float4(0.f, 0.f, 0.f, 0.f);
    for (int base = 0; base < n; base += 128) {
        int m = min(n - base, 128);
        __syncthreads();
        if (t < m) epack[t] = csr[s0 + base + t];
        __syncthreads();
#pragma unroll 2
        for (int j = g; j < m; j += 4) {
            int p = epack[j];
            int src = p & 0xFFFF;
            int rel = (p >> 16) & 7;
            float s = sdinv[rel];
            uint2 v = *(const uint2*)&xWall[(size_t)src * 1024 + rel * 128 + l * 4];
            acc.x += s * __uint_as_float(v.x << 16);
            acc.y += s * __uint_as_float(v.x & 0xFFFF0000u);
            acc.z += s * __uint_as_float(v.y << 16);
            acc.w += s * __uint_as_float(v.y & 0xFFFF0000u);
        }
    }
    *(float4*)&sacc[t * 4] = acc;
    __syncthreads();
    float r = 0.f;
#pragma unroll
    for (int gg = 0; gg < 4; ++gg) r += sacc[(gg * 32 + (t >> 2)) * 4 + (t & 3)];
    out[(size_t)dst * D + t] += r;
}

// ---------------------------------------------------------------------------
extern "C" void kernel_launch(void* const* d_in, const int* in_sizes, int n_in,
                              void* d_out, int out_size, void* d_ws, size_t ws_size,
                              hipStream_t stream) {
    const float* x         = (const float*)d_in[0];
    const float* bases     = (const float*)d_in[1];
    const float* coeff     = (const float*)d_in[2];
    const float* self_loop = (const float*)d_in[3];
    const int*   ei        = (const int*)d_in[4];
    const int*   et        = (const int*)d_in[5];
    float* out = (float*)d_out;

    char* ws = (char*)d_ws;
    size_t o = 0;
    auto alloc = [&](size_t bytes) { size_t r = o; o += (bytes + 255) & ~(size_t)255; return r; };
    size_t o_ccnt   = alloc(256 * 4);                        // zeroed
    size_t zero_end = o;
    size_t o_coff   = alloc((NCB + 1) * 4);
    size_t o_gcur   = alloc(NCB * 4);
    size_t o_rowoff = alloc((size_t)(N_NODES + 1) * 4);
    size_t o_recA   = alloc((size_t)N_EDGES * 4);
    size_t o_csr    = alloc((size_t)N_EDGES * 4);
    size_t o_dinv   = alloc((size_t)N_NODES * 8 * 4);
    size_t o_WbT    = alloc((size_t)9 * 16384 * 2);
    size_t o_xb     = alloc((size_t)N_NODES * D * 2);
    size_t o_xW     = alloc((size_t)N_NODES * 1024 * 2);
    if (ws_size < o) return;

    int*            ccnt    = (int*)(ws + o_ccnt);
    int*            coff    = (int*)(ws + o_coff);
    int*            gcur    = (int*)(ws + o_gcur);
    int*            row_off = (int*)(ws + o_rowoff);
    unsigned int*   recA    = (unsigned int*)(ws + o_recA);
    int*            csr     = (int*)(ws + o_csr);
    float*          dinv    = (float*)(ws + o_dinv);
    unsigned short* WbT     = (unsigned short*)(ws + o_WbT);
    unsigned short* xb      = (unsigned short*)(ws + o_xb);
    unsigned short* xW      = (unsigned short*)(ws + o_xW);

    hipMemsetAsync(ccnt, 0, zero_end, stream);

    k_makeW<<<dim3(9, 8), 256, 0, stream>>>(coeff, bases, self_loop, WbT);
    k_cvtx<<<3125, 256, 0, stream>>>(x, xb);
    k_histA<<<(N_EDGES + 1023) / 1024, 256, 0, stream>>>(ei, ccnt);
    k_scanA1<<<1, 256, 0, stream>>>(ccnt, coff, gcur, row_off);
    k_bucketA<<<(N_EDGES + ACHUNK - 1) / ACHUNK, 256, 0, stream>>>(ei, et, gcur, recA);
    k_buildC<<<NCB, 256, 0, stream>>>(recA, coff, row_off, csr, dinv);

    k_mm_big<<<391, 512, 0, stream>>>(xb, WbT, xW, out, N_NODES);
    k_gather<<<N_NODES, 128, 0, stream>>>(xW, csr, row_off, dinv, out);
}

// Round 9
// 147.538 us; speedup vs baseline: 5.1954x; 1.0242x over previous
//
#include <hip/hip_runtime.h>
#include <hip/hip_bf16.h>

#define N_NODES 50000
#define N_EDGES 800000
#define N_REL 8
#define N_BASES 16
#define D 128
#define NCB 196   // coarse buckets of 256 dsts

typedef __attribute__((ext_vector_type(8))) short bf16x8;
typedef __attribute__((ext_vector_type(4))) float f32x4;

__device__ inline unsigned short f2bf(float f) {
    unsigned int x = __float_as_uint(f);
    unsigned int r = x + 0x7FFFu + ((x >> 16) & 1u);
    return (unsigned short)(r >> 16);
}
__device__ inline float bf2f(unsigned short u) {
    return __uint_as_float(((unsigned int)u) << 16);
}

// ---------------------------------------------------------------------------
// WbT[r][o][i] = bf16( (r<8 ? sum_b coeff[r,b]*bases[b] : self_loop)[i][o] )
__global__ __launch_bounds__(256) void k_makeW(const float* __restrict__ coeff,
                                               const float* __restrict__ bases,
                                               const float* __restrict__ self_loop,
                                               unsigned short* __restrict__ WbT) {
    const int r = blockIdx.x, os = blockIdx.y;
    const int t = threadIdx.x;
    __shared__ unsigned short tile[128][17];   // [i][o_local]
    const int i = t >> 1, ob = (t & 1) * 8;
    const int gcol = os * 16 + ob;
    float s[8];
    if (r < 8) {
        float c[16];
#pragma unroll
        for (int b = 0; b < 16; ++b) c[b] = coeff[r * 16 + b];
#pragma unroll
        for (int j = 0; j < 8; ++j) s[j] = 0.f;
#pragma unroll
        for (int b = 0; b < 16; ++b) {
            const float* bp = bases + b * 16384 + i * 128 + gcol;
            float4 v0 = *(const float4*)bp;
            float4 v1 = *(const float4*)(bp + 4);
            s[0] += c[b] * v0.x; s[1] += c[b] * v0.y; s[2] += c[b] * v0.z; s[3] += c[b] * v0.w;
            s[4] += c[b] * v1.x; s[5] += c[b] * v1.y; s[6] += c[b] * v1.z; s[7] += c[b] * v1.w;
        }
    } else {
        const float* sp = self_loop + i * 128 + gcol;
        float4 v0 = *(const float4*)sp;
        float4 v1 = *(const float4*)(sp + 4);
        s[0] = v0.x; s[1] = v0.y; s[2] = v0.z; s[3] = v0.w;
        s[4] = v1.x; s[5] = v1.y; s[6] = v1.z; s[7] = v1.w;
    }
#pragma unroll
    for (int j = 0; j < 8; ++j) tile[i][ob + j] = f2bf(s[j]);
    __syncthreads();
    const int o = t >> 4, ic = (t & 15) << 3;
    unsigned int pk[4];
#pragma unroll
    for (int j = 0; j < 4; ++j)
        pk[j] = (unsigned int)tile[ic + j * 2][o] | ((unsigned int)tile[ic + j * 2 + 1][o] << 16);
    *(int4*)&WbT[(size_t)r * 16384 + (os * 16 + o) * 128 + ic] = *(int4*)pk;
}

// ---------------------------------------------------------------------------
// xb = bf16(x)
__global__ __launch_bounds__(256) void k_cvtx(const float* __restrict__ x,
                                              unsigned short* __restrict__ xb) {
    int i = blockIdx.x * 256 + threadIdx.x;   // grid exact: 3125*256 = 800000
    const float4* xp = (const float4*)x;
    float4 a = xp[i * 2], b = xp[i * 2 + 1];
    int4 o;
    o.x = (int)f2bf(a.x) | ((int)f2bf(a.y) << 16);
    o.y = (int)f2bf(a.z) | ((int)f2bf(a.w) << 16);
    o.z = (int)f2bf(b.x) | ((int)f2bf(b.y) << 16);
    o.w = (int)f2bf(b.z) | ((int)f2bf(b.w) << 16);
    ((int4*)xb)[i] = o;
}

// ---------------------------------------------------------------------------
// coarse histogram of dst>>8
__global__ __launch_bounds__(256) void k_histA(const int* __restrict__ ei,
                                               int* __restrict__ ccnt) {
    __shared__ int h[256];
    int t = threadIdx.x;
    h[t] = 0;
    __syncthreads();
    int idx = blockIdx.x * 1024 + t * 4;
    if (idx < N_EDGES) {
        int4 d = *(const int4*)&ei[N_EDGES + idx];
        atomicAdd(&h[d.x >> 8], 1);
        atomicAdd(&h[d.y >> 8], 1);
        atomicAdd(&h[d.z >> 8], 1);
        atomicAdd(&h[d.w >> 8], 1);
    }
    __syncthreads();
    if (t < NCB && h[t]) atomicAdd(&ccnt[t], h[t]);
}

// ---------------------------------------------------------------------------
// exclusive scan of ccnt[196] -> coff[197], gcur; row_off[N] = total
__global__ __launch_bounds__(256) void k_scanA1(const int* __restrict__ ccnt,
                                                int* __restrict__ coff,
                                                int* __restrict__ gcur,
                                                int* __restrict__ row_off) {
    int t = threadIdx.x;
    int v = (t < NCB) ? ccnt[t] : 0;
    int lane = t & 63, wv = t >> 6;
    int inc = v;
#pragma unroll
    for (int off = 1; off < 64; off <<= 1) {
        int y = __shfl_up(inc, off);
        if (lane >= off) inc += y;
    }
    __shared__ int ws4[4];
    if (lane == 63) ws4[wv] = inc;
    __syncthreads();
    int wb = 0;
    for (int i = 0; i < wv; ++i) wb += ws4[i];
    int ex = wb + inc - v;
    if (t < NCB) { coff[t] = ex; gcur[t] = ex; }
    if (t == NCB - 1) { coff[NCB] = ex + v; row_off[N_NODES] = ex + v; }
}

// ---------------------------------------------------------------------------
// bucket edges into coarse segments; rec = src | rel<<16 | (dst&255)<<19
#define ACHUNK 2048
__global__ __launch_bounds__(256) void k_bucketA(const int* __restrict__ ei,
                                                 const int* __restrict__ et,
                                                 int* __restrict__ gcur,
                                                 unsigned int* __restrict__ recA) {
    __shared__ int lcnt[NCB], lbase[NCB];
    const int base = blockIdx.x * ACHUNK;
    const int t = threadIdx.x;
    if (t < NCB) lcnt[t] = 0;
    __syncthreads();
    unsigned int rec[8];
    int mb[8];
#pragma unroll
    for (int i = 0; i < 8; ++i) {
        int e = base + t + i * 256;
        if (e < N_EDGES) {
            int src = ei[e];
            int dst = ei[N_EDGES + e];
            int r = et[e];
            rec[i] = (unsigned)src | ((unsigned)r << 16) | ((unsigned)(dst & 255) << 19);
            mb[i] = dst >> 8;
            atomicAdd(&lcnt[mb[i]], 1);
        } else mb[i] = -1;
    }
    __syncthreads();
    if (t < NCB) lbase[t] = lcnt[t] ? atomicAdd(&gcur[t], lcnt[t]) : 0;
    __syncthreads();
    if (t < NCB) lcnt[t] = 0;
    __syncthreads();
#pragma unroll
    for (int i = 0; i < 8; ++i) {
        if (mb[i] < 0) continue;
        int pos = lbase[mb[i]] + atomicAdd(&lcnt[mb[i]], 1);
        recA[pos] = rec[i];
    }
}

// ---------------------------------------------------------------------------
// per coarse bucket: dst-sorted csr + row_off + dinv (all LDS atomics)
__global__ __launch_bounds__(256) void k_buildC(const unsigned int* __restrict__ recA,
                                                const int* __restrict__ coff,
                                                int* __restrict__ row_off,
                                                int* __restrict__ csr,
                                                float* __restrict__ dinv) {
    const int b = blockIdx.x, t = threadIdx.x;
    const int s0 = coff[b], s1 = coff[b + 1];
    __shared__ int h2[2048];   // (dst&255)*8 + rel
    __shared__ int cur[256];
    __shared__ int ws4[4];
    for (int i = t; i < 2048; i += 256) h2[i] = 0;
    __syncthreads();
    for (int i = s0 + t; i < s1; i += 256) {
        unsigned int p = recA[i];
        atomicAdd(&h2[((p >> 19) & 255) * 8 + ((p >> 16) & 7)], 1);
    }
    __syncthreads();
    int sum = 0;
#pragma unroll
    for (int r = 0; r < 8; ++r) sum += h2[t * 8 + r];
    int lane = t & 63, wv = t >> 6;
    int inc = sum;
#pragma unroll
    for (int off = 1; off < 64; off <<= 1) {
        int y = __shfl_up(inc, off);
        if (lane >= off) inc += y;
    }
    if (lane == 63) ws4[wv] = inc;
    __syncthreads();
    int wb = 0;
    for (int i = 0; i < wv; ++i) wb += ws4[i];
    int ex = wb + inc - sum;          // exclusive per-dst offset within bucket
    cur[t] = ex;
    int dst = (b << 8) + t;
    if (dst < N_NODES) row_off[dst] = s0 + ex;
    __syncthreads();
    for (int i = t; i < 2048; i += 256) {
        int d2 = (b << 8) + (i >> 3);
        if (d2 < N_NODES) dinv[(size_t)d2 * 8 + (i & 7)] = 1.0f / fmaxf((float)h2[i], 1.0f);
    }
    for (int i = s0 + t; i < s1; i += 256) {
        unsigned int p = recA[i];
        int pos = s0 + atomicAdd(&cur[(p >> 19) & 255], 1);
        csr[pos] = (int)(p & 0x7FFFF);   // src | rel<<16
    }
}

// ---------------------------------------------------------------------------
// one panel per block: grid (391, 9). Panels 0-7 -> bf16 xW (LDS-staged
// coalesced stores); panel 8 (self) -> fp32 out. Blocks independent -> store
// latency overlaps across blocks (no serial per-panel vmcnt drains).
__global__ __launch_bounds__(512) void k_mm9(const unsigned short* __restrict__ xb,
                                             const unsigned short* __restrict__ WbT,
                                             unsigned short* __restrict__ xW,
                                             float* __restrict__ out, int M) {
    __shared__ unsigned short As[128][136];
    __shared__ unsigned short Bs[128][136];
    const int rb = blockIdx.x * 128;
    const int p = blockIdx.y;
    const int t = threadIdx.x;
    const unsigned short* Bsrc = WbT + p * 16384;

#pragma unroll
    for (int i = 0; i < 4; ++i) {
        int f = t + i * 512;
        int row = f >> 4, c8 = (f & 15) << 3;
        int gr = rb + row;
        int4 v = make_int4(0, 0, 0, 0);
        if (gr < M) v = *(const int4*)&xb[(size_t)gr * D + c8];
        *(int4*)&As[row][c8] = v;
        *(int4*)&Bs[row][c8] = *(const int4*)&Bsrc[row * 128 + c8];
    }
    __syncthreads();

    const int w = t >> 6, lane = t & 63;
    const int rh = (w >> 2) * 64, cq = (w & 3) * 32;
    const int lr = lane & 15, lg = lane >> 4;

    f32x4 acc[4][2] = {};
#pragma unroll
    for (int kk = 0; kk < 4; ++kk) {
        int ko = kk * 32 + lg * 8;
        bf16x8 a[4], b[2];
#pragma unroll
        for (int m = 0; m < 4; ++m) a[m] = *(const bf16x8*)&As[rh + m * 16 + lr][ko];
#pragma unroll
        for (int n = 0; n < 2; ++n) b[n] = *(const bf16x8*)&Bs[cq + n * 16 + lr][ko];
#pragma unroll
        for (int m = 0; m < 4; ++m)
#pragma unroll
            for (int n = 0; n < 2; ++n)
                acc[m][n] = __builtin_amdgcn_mfma_f32_16x16x32_bf16(a[m], b[n], acc[m][n], 0, 0, 0);
    }

    if (p < 8) {
        __syncthreads();   // all waves done reading Bs
#pragma unroll
        for (int m = 0; m < 4; ++m)
#pragma unroll
            for (int n = 0; n < 2; ++n)
#pragma unroll
                for (int q = 0; q < 4; ++q)
                    Bs[rh + m * 16 + lg * 4 + q][cq + n * 16 + lr] = f2bf(acc[m][n][q]);
        __syncthreads();
#pragma unroll
        for (int i = 0; i < 4; ++i) {
            int f = t + i * 512;
            int row = f >> 4, c8 = (f & 15) << 3;
            int gr = rb + row;
            if (gr < M) *(int4*)&xW[(size_t)gr * 1024 + p * 128 + c8] = *(const int4*)&Bs[row][c8];
        }
    } else {
#pragma unroll
        for (int m = 0; m < 4; ++m)
#pragma unroll
            for (int n = 0; n < 2; ++n)
#pragma unroll
                for (int q = 0; q < 4; ++q) {
                    int grow = rb + rh + m * 16 + lg * 4 + q;
                    int col = cq + n * 16 + lr;
                    if (grow < M) out[(size_t)grow * 128 + col] = acc[m][n][q];
                }
    }
}

// ---------------------------------------------------------------------------
// wave-per-dst gather: 64 lanes cover the 256B xW row (uint/lane), edges
// staged 64-at-a-time in LDS, 8-deep unrolled loads for MLP, float2 RMW out.
__global__ __launch_bounds__(256) void k_gather2(const unsigned short* __restrict__ xW,
                                                 const int* __restrict__ csr,
                                                 const int* __restrict__ row_off,
                                                 const float* __restrict__ dinv,
                                                 float* __restrict__ out) {
    __shared__ int eL[4][64];
    __shared__ float dv[4][16];
    const int t = threadIdx.x;
    const int wv = t >> 6, lane = t & 63;
    const int dst = blockIdx.x * 4 + wv;          // grid 12500 exact
    const int s0 = row_off[dst], s1 = row_off[dst + 1];
    const int n = s1 - s0;
    if (lane < 8) dv[wv][lane] = dinv[(size_t)dst * 8 + lane];
    else if (lane < 16) dv[wv][lane] = 0.f;       // sentinel scale (rel=8)
    if (n <= 0) return;                           // wave-uniform
    float a0 = 0.f, a1 = 0.f;
    const int loff = lane * 2;
    for (int base = 0; base < n; base += 64) {
        int m = min(n - base, 64);
        int e = (lane < m) ? csr[s0 + base + lane] : (8 << 16);
        eL[wv][lane] = e;
        int mr = (m + 7) & ~7;
        for (int jb = 0; jb < mr; jb += 8) {
            float sc[8];
            unsigned vv[8];
#pragma unroll
            for (int k = 0; k < 8; ++k) {
                int ee = eL[wv][jb + k];
                int src = ee & 0xFFFF;
                int rl = (ee >> 16) & 15;         // 0..7 real, 8 sentinel
                sc[k] = dv[wv][rl];
                vv[k] = *(const unsigned*)&xW[(size_t)src * 1024 + rl * 128 + loff];
            }
#pragma unroll
            for (int k = 0; k < 8; ++k) {
                a0 += sc[k] * __uint_as_float(vv[k] << 16);
                a1 += sc[k] * __uint_as_float(vv[k] & 0xFFFF0000u);
            }
        }
    }
    float2* op = (float2*)&out[(size_t)dst * 128 + loff];
    float2 cur = *op;
    cur.x += a0;
    cur.y += a1;
    *op = cur;
}

// ---------------------------------------------------------------------------
extern "C" void kernel_launch(void* const* d_in, const int* in_sizes, int n_in,
                              void* d_out, int out_size, void* d_ws, size_t ws_size,
                              hipStream_t stream) {
    const float* x         = (const float*)d_in[0];
    const float* bases     = (const float*)d_in[1];
    const float* coeff     = (const float*)d_in[2];
    const float* self_loop = (const float*)d_in[3];
    const int*   ei        = (const int*)d_in[4];
    const int*   et        = (const int*)d_in[5];
    float* out = (float*)d_out;

    char* ws = (char*)d_ws;
    size_t o = 0;
    auto alloc = [&](size_t bytes) { size_t r = o; o += (bytes + 255) & ~(size_t)255; return r; };
    size_t o_ccnt   = alloc(256 * 4);                        // zeroed
    size_t zero_end = o;
    size_t o_coff   = alloc((NCB + 1) * 4);
    size_t o_gcur   = alloc(NCB * 4);
    size_t o_rowoff = alloc((size_t)(N_NODES + 1) * 4);
    size_t o_recA   = alloc((size_t)N_EDGES * 4);
    size_t o_csr    = alloc((size_t)N_EDGES * 4);
    size_t o_dinv   = alloc((size_t)N_NODES * 8 * 4);
    size_t o_WbT    = alloc((size_t)9 * 16384 * 2);
    size_t o_xb     = alloc((size_t)N_NODES * D * 2);
    size_t o_xW     = alloc((size_t)N_NODES * 1024 * 2 + 4096);
    if (ws_size < o) return;

    int*            ccnt    = (int*)(ws + o_ccnt);
    int*            coff    = (int*)(ws + o_coff);
    int*            gcur    = (int*)(ws + o_gcur);
    int*            row_off = (int*)(ws + o_rowoff);
    unsigned int*   recA    = (unsigned int*)(ws + o_recA);
    int*            csr     = (int*)(ws + o_csr);
    float*          dinv    = (float*)(ws + o_dinv);
    unsigned short* WbT     = (unsigned short*)(ws + o_WbT);
    unsigned short* xb      = (unsigned short*)(ws + o_xb);
    unsigned short* xW      = (unsigned short*)(ws + o_xW);

    hipMemsetAsync(ccnt, 0, zero_end, stream);

    k_makeW<<<dim3(9, 8), 256, 0, stream>>>(coeff, bases, self_loop, WbT);
    k_cvtx<<<3125, 256, 0, stream>>>(x, xb);
    k_histA<<<(N_EDGES + 1023) / 1024, 256, 0, stream>>>(ei, ccnt);
    k_scanA1<<<1, 256, 0, stream>>>(ccnt, coff, gcur, row_off);
    k_bucketA<<<(N_EDGES + ACHUNK - 1) / ACHUNK, 256, 0, stream>>>(ei, et, gcur, recA);
    k_buildC<<<NCB, 256, 0, stream>>>(recA, coff, row_off, csr, dinv);

    k_mm9<<<dim3(391, 9), 512, 0, stream>>>(xb, WbT, xW, out, N_NODES);
    k_gather2<<<12500, 256, 0, stream>>>(xW, csr, row_off, dinv, out);
}

// Round 10
// 130.265 us; speedup vs baseline: 5.8843x; 1.1326x over previous
//
#include <hip/hip_runtime.h>
#include <hip/hip_bf16.h>

#define N_NODES 50000
#define N_EDGES 800000
#define N_REL 8
#define N_BASES 16
#define D 128
#define NCB 196   // coarse buckets of 256 dsts
#define ACHUNK 2048

typedef __attribute__((ext_vector_type(8))) short bf16x8;
typedef __attribute__((ext_vector_type(4))) float f32x4;

__device__ inline unsigned short f2bf(float f) {
    unsigned int x = __float_as_uint(f);
    unsigned int r = x + 0x7FFFu + ((x >> 16) & 1u);
    return (unsigned short)(r >> 16);
}
__device__ inline float bf2f(unsigned short u) {
    return __uint_as_float(((unsigned int)u) << 16);
}

// ---------------------------------------------------------------------------
// K1: fused {histA (blocks 0..781), cvtx (782..3906), makeW (3907..3978)}
#define K1_HIST 782
#define K1_CVT  3125
#define K1_MKW  72
__global__ __launch_bounds__(256) void k_setup1(const float* __restrict__ x,
                                                const float* __restrict__ coeff,
                                                const float* __restrict__ bases,
                                                const float* __restrict__ self_loop,
                                                const int* __restrict__ ei,
                                                unsigned short* __restrict__ xb,
                                                unsigned short* __restrict__ WbT,
                                                int* __restrict__ ccnt) {
    __shared__ int h[256];
    __shared__ unsigned short tile[128][17];
    const int b = blockIdx.x;
    const int t = threadIdx.x;

    if (b < K1_HIST) {
        // ---- coarse histogram of dst>>8
        h[t] = 0;
        __syncthreads();
        int idx = b * 1024 + t * 4;
        if (idx < N_EDGES) {
            int4 d = *(const int4*)&ei[N_EDGES + idx];
            atomicAdd(&h[d.x >> 8], 1);
            atomicAdd(&h[d.y >> 8], 1);
            atomicAdd(&h[d.z >> 8], 1);
            atomicAdd(&h[d.w >> 8], 1);
        }
        __syncthreads();
        if (t < NCB && h[t]) atomicAdd(&ccnt[t], h[t]);
    } else if (b < K1_HIST + K1_CVT) {
        // ---- xb = bf16(x)
        int i = (b - K1_HIST) * 256 + t;
        const float4* xp = (const float4*)x;
        float4 a = xp[i * 2], bb = xp[i * 2 + 1];
        int4 o;
        o.x = (int)f2bf(a.x) | ((int)f2bf(a.y) << 16);
        o.y = (int)f2bf(a.z) | ((int)f2bf(a.w) << 16);
        o.z = (int)f2bf(bb.x) | ((int)f2bf(bb.y) << 16);
        o.w = (int)f2bf(bb.z) | ((int)f2bf(bb.w) << 16);
        ((int4*)xb)[i] = o;
    } else {
        // ---- WbT[r][o][i] = bf16((r<8 ? sum_b c*bases : self_loop)[i][o])
        int local = b - K1_HIST - K1_CVT;
        const int r = local >> 3, os = local & 7;
        const int i = t >> 1, ob = (t & 1) * 8;
        const int gcol = os * 16 + ob;
        float s[8];
        if (r < 8) {
            float c[16];
#pragma unroll
            for (int bb = 0; bb < 16; ++bb) c[bb] = coeff[r * 16 + bb];
#pragma unroll
            for (int j = 0; j < 8; ++j) s[j] = 0.f;
#pragma unroll
            for (int bb = 0; bb < 16; ++bb) {
                const float* bp = bases + bb * 16384 + i * 128 + gcol;
                float4 v0 = *(const float4*)bp;
                float4 v1 = *(const float4*)(bp + 4);
                s[0] += c[bb] * v0.x; s[1] += c[bb] * v0.y; s[2] += c[bb] * v0.z; s[3] += c[bb] * v0.w;
                s[4] += c[bb] * v1.x; s[5] += c[bb] * v1.y; s[6] += c[bb] * v1.z; s[7] += c[bb] * v1.w;
            }
        } else {
            const float* sp = self_loop + i * 128 + gcol;
            float4 v0 = *(const float4*)sp;
            float4 v1 = *(const float4*)(sp + 4);
            s[0] = v0.x; s[1] = v0.y; s[2] = v0.z; s[3] = v0.w;
            s[4] = v1.x; s[5] = v1.y; s[6] = v1.z; s[7] = v1.w;
        }
#pragma unroll
        for (int j = 0; j < 8; ++j) tile[i][ob + j] = f2bf(s[j]);
        __syncthreads();
        const int o = t >> 4, ic = (t & 15) << 3;
        unsigned int pk[4];
#pragma unroll
        for (int j = 0; j < 4; ++j)
            pk[j] = (unsigned int)tile[ic + j * 2][o] | ((unsigned int)tile[ic + j * 2 + 1][o] << 16);
        *(int4*)&WbT[(size_t)r * 16384 + (os * 16 + o) * 128 + ic] = *(int4*)pk;
    }
}

// ---------------------------------------------------------------------------
// exclusive scan of ccnt[196] -> coff[197], gcur; row_off[N] = total
__global__ __launch_bounds__(256) void k_scanA1(const int* __restrict__ ccnt,
                                                int* __restrict__ coff,
                                                int* __restrict__ gcur,
                                                int* __restrict__ row_off) {
    int t = threadIdx.x;
    int v = (t < NCB) ? ccnt[t] : 0;
    int lane = t & 63, wv = t >> 6;
    int inc = v;
#pragma unroll
    for (int off = 1; off < 64; off <<= 1) {
        int y = __shfl_up(inc, off);
        if (lane >= off) inc += y;
    }
    __shared__ int ws4[4];
    if (lane == 63) ws4[wv] = inc;
    __syncthreads();
    int wb = 0;
    for (int i = 0; i < wv; ++i) wb += ws4[i];
    int ex = wb + inc - v;
    if (t < NCB) { coff[t] = ex; gcur[t] = ex; }
    if (t == NCB - 1) { coff[NCB] = ex + v; row_off[N_NODES] = ex + v; }
}

// ---------------------------------------------------------------------------
// K3: fused {bucketA (blocks 0..390, dispatched first), mm9 (391..3918)}.
// mm9 local blocks are XCD-swizzled so all 9 panels of a row-tile share an
// XCD L2 (As reuse): c=(local+7)&7, slot=local>>3, tile=c*49+slot/9.
__global__ __launch_bounds__(512) void k_work(const int* __restrict__ ei,
                                              const int* __restrict__ et,
                                              int* __restrict__ gcur,
                                              unsigned int* __restrict__ recA,
                                              const unsigned short* __restrict__ xb,
                                              const unsigned short* __restrict__ WbT,
                                              unsigned short* __restrict__ xW,
                                              float* __restrict__ out, int M) {
    __shared__ unsigned short As[128][136];
    __shared__ unsigned short Bs[128][136];
    __shared__ int lcnt[NCB], lbase[NCB];
    const int bid = blockIdx.x;
    const int t = threadIdx.x;

    if (bid < 391) {
        // ---- bucketA: 2048 edges, 512 threads x 4
        const int base = bid * ACHUNK;
        if (t < NCB) lcnt[t] = 0;
        __syncthreads();
        unsigned int rec[4];
        int mb[4];
#pragma unroll
        for (int i = 0; i < 4; ++i) {
            int e = base + t + i * 512;
            if (e < N_EDGES) {
                int src = ei[e];
                int dst = ei[N_EDGES + e];
                int r = et[e];
                rec[i] = (unsigned)src | ((unsigned)r << 16) | ((unsigned)(dst & 255) << 19);
                mb[i] = dst >> 8;
                atomicAdd(&lcnt[mb[i]], 1);
            } else mb[i] = -1;
        }
        __syncthreads();
        if (t < NCB) lbase[t] = lcnt[t] ? atomicAdd(&gcur[t], lcnt[t]) : 0;
        __syncthreads();
        if (t < NCB) lcnt[t] = 0;
        __syncthreads();
#pragma unroll
        for (int i = 0; i < 4; ++i) {
            if (mb[i] < 0) continue;
            int pos = lbase[mb[i]] + atomicAdd(&lcnt[mb[i]], 1);
            recA[pos] = rec[i];
        }
        return;
    }

    // ---- mm9, XCD-swizzled
    const int local = bid - 391;            // 0..3527
    const int c = (local + 7) & 7;          // presumed XCD of this block
    const int slot = local >> 3;            // 0..440
    const int tile = c * 49 + slot / 9;
    const int p = slot % 9;
    if (tile >= 391) return;
    const int rb = tile * 128;
    const unsigned short* Bsrc = WbT + p * 16384;

#pragma unroll
    for (int i = 0; i < 4; ++i) {
        int f = t + i * 512;
        int row = f >> 4, c8 = (f & 15) << 3;
        int gr = rb + row;
        int4 v = make_int4(0, 0, 0, 0);
        if (gr < M) v = *(const int4*)&xb[(size_t)gr * D + c8];
        *(int4*)&As[row][c8] = v;
        *(int4*)&Bs[row][c8] = *(const int4*)&Bsrc[row * 128 + c8];
    }
    __syncthreads();

    const int w = t >> 6, lane = t & 63;
    const int rh = (w >> 2) * 64, cq = (w & 3) * 32;
    const int lr = lane & 15, lg = lane >> 4;

    f32x4 acc[4][2] = {};
#pragma unroll
    for (int kk = 0; kk < 4; ++kk) {
        int ko = kk * 32 + lg * 8;
        bf16x8 a[4], b[2];
#pragma unroll
        for (int m = 0; m < 4; ++m) a[m] = *(const bf16x8*)&As[rh + m * 16 + lr][ko];
#pragma unroll
        for (int n = 0; n < 2; ++n) b[n] = *(const bf16x8*)&Bs[cq + n * 16 + lr][ko];
#pragma unroll
        for (int m = 0; m < 4; ++m)
#pragma unroll
            for (int n = 0; n < 2; ++n)
                acc[m][n] = __builtin_amdgcn_mfma_f32_16x16x32_bf16(a[m], b[n], acc[m][n], 0, 0, 0);
    }

    if (p < 8) {
        __syncthreads();   // all waves done reading Bs
#pragma unroll
        for (int m = 0; m < 4; ++m)
#pragma unroll
            for (int n = 0; n < 2; ++n)
#pragma unroll
                for (int q = 0; q < 4; ++q)
                    Bs[rh + m * 16 + lg * 4 + q][cq + n * 16 + lr] = f2bf(acc[m][n][q]);
        __syncthreads();
#pragma unroll
        for (int i = 0; i < 4; ++i) {
            int f = t + i * 512;
            int row = f >> 4, c8 = (f & 15) << 3;
            int gr = rb + row;
            if (gr < M) *(int4*)&xW[(size_t)gr * 1024 + p * 128 + c8] = *(const int4*)&Bs[row][c8];
        }
    } else {
#pragma unroll
        for (int m = 0; m < 4; ++m)
#pragma unroll
            for (int n = 0; n < 2; ++n)
#pragma unroll
                for (int q = 0; q < 4; ++q) {
                    int grow = rb + rh + m * 16 + lg * 4 + q;
                    int col = cq + n * 16 + lr;
                    if (grow < M) out[(size_t)grow * 128 + col] = acc[m][n][q];
                }
    }
}

// ---------------------------------------------------------------------------
// per coarse bucket: dst-sorted csr + row_off + dinv (all LDS atomics)
__global__ __launch_bounds__(256) void k_buildC(const unsigned int* __restrict__ recA,
                                                const int* __restrict__ coff,
                                                int* __restrict__ row_off,
                                                int* __restrict__ csr,
                                                float* __restrict__ dinv) {
    const int b = blockIdx.x, t = threadIdx.x;
    const int s0 = coff[b], s1 = coff[b + 1];
    __shared__ int h2[2048];   // (dst&255)*8 + rel
    __shared__ int cur[256];
    __shared__ int ws4[4];
    for (int i = t; i < 2048; i += 256) h2[i] = 0;
    __syncthreads();
    for (int i = s0 + t; i < s1; i += 256) {
        unsigned int p = recA[i];
        atomicAdd(&h2[((p >> 19) & 255) * 8 + ((p >> 16) & 7)], 1);
    }
    __syncthreads();
    int sum = 0;
#pragma unroll
    for (int r = 0; r < 8; ++r) sum += h2[t * 8 + r];
    int lane = t & 63, wv = t >> 6;
    int inc = sum;
#pragma unroll
    for (int off = 1; off < 64; off <<= 1) {
        int y = __shfl_up(inc, off);
        if (lane >= off) inc += y;
    }
    if (lane == 63) ws4[wv] = inc;
    __syncthreads();
    int wb = 0;
    for (int i = 0; i < wv; ++i) wb += ws4[i];
    int ex = wb + inc - sum;
    cur[t] = ex;
    int dst = (b << 8) + t;
    if (dst < N_NODES) row_off[dst] = s0 + ex;
    __syncthreads();
    for (int i = t; i < 2048; i += 256) {
        int d2 = (b << 8) + (i >> 3);
        if (d2 < N_NODES) dinv[(size_t)d2 * 8 + (i & 7)] = 1.0f / fmaxf((float)h2[i], 1.0f);
    }
    for (int i = s0 + t; i < s1; i += 256) {
        unsigned int p = recA[i];
        int pos = s0 + atomicAdd(&cur[(p >> 19) & 255], 1);
        csr[pos] = (int)(p & 0x7FFFF);   // src | rel<<16
    }
}

// ---------------------------------------------------------------------------
// wave-per-dst gather: 64 lanes cover the 256B xW row, edges staged in LDS,
// 8-deep unrolled loads for MLP, float2 RMW out.
__global__ __launch_bounds__(256) void k_gather2(const unsigned short* __restrict__ xW,
                                                 const int* __restrict__ csr,
                                                 const int* __restrict__ row_off,
                                                 const float* __restrict__ dinv,
                                                 float* __restrict__ out) {
    __shared__ int eL[4][64];
    __shared__ float dv[4][16];
    const int t = threadIdx.x;
    const int wv = t >> 6, lane = t & 63;
    const int dst = blockIdx.x * 4 + wv;          // grid 12500 exact
    const int s0 = row_off[dst], s1 = row_off[dst + 1];
    const int n = s1 - s0;
    if (lane < 8) dv[wv][lane] = dinv[(size_t)dst * 8 + lane];
    else if (lane < 16) dv[wv][lane] = 0.f;       // sentinel scale (rel>=8)
    if (n <= 0) return;                           // wave-uniform
    float a0 = 0.f, a1 = 0.f;
    const int loff = lane * 2;
    for (int base = 0; base < n; base += 64) {
        int m = min(n - base, 64);
        int e = (lane < m) ? csr[s0 + base + lane] : (8 << 16);
        eL[wv][lane] = e;
        int mr = (m + 7) & ~7;
        for (int jb = 0; jb < mr; jb += 8) {
            float sc[8];
            unsigned vv[8];
#pragma unroll
            for (int k = 0; k < 8; ++k) {
                int ee = eL[wv][jb + k];
                int src = ee & 0xFFFF;
                int rl = (ee >> 16) & 15;
                sc[k] = dv[wv][rl];
                vv[k] = *(const unsigned*)&xW[(size_t)src * 1024 + rl * 128 + loff];
            }
#pragma unroll
            for (int k = 0; k < 8; ++k) {
                a0 += sc[k] * __uint_as_float(vv[k] << 16);
                a1 += sc[k] * __uint_as_float(vv[k] & 0xFFFF0000u);
            }
        }
    }
    float2* op = (float2*)&out[(size_t)dst * 128 + loff];
    float2 cur = *op;
    cur.x += a0;
    cur.y += a1;
    *op = cur;
}

// ---------------------------------------------------------------------------
extern "C" void kernel_launch(void* const* d_in, const int* in_sizes, int n_in,
                              void* d_out, int out_size, void* d_ws, size_t ws_size,
                              hipStream_t stream) {
    const float* x         = (const float*)d_in[0];
    const float* bases     = (const float*)d_in[1];
    const float* coeff     = (const float*)d_in[2];
    const float* self_loop = (const float*)d_in[3];
    const int*   ei        = (const int*)d_in[4];
    const int*   et        = (const int*)d_in[5];
    float* out = (float*)d_out;

    char* ws = (char*)d_ws;
    size_t o = 0;
    auto alloc = [&](size_t bytes) { size_t r = o; o += (bytes + 255) & ~(size_t)255; return r; };
    size_t o_ccnt   = alloc(256 * 4);                        // zeroed
    size_t zero_end = o;
    size_t o_coff   = alloc((NCB + 1) * 4);
    size_t o_gcur   = alloc(NCB * 4);
    size_t o_rowoff = alloc((size_t)(N_NODES + 1) * 4);
    size_t o_recA   = alloc((size_t)N_EDGES * 4);
    size_t o_csr    = alloc((size_t)N_EDGES * 4);
    size_t o_dinv   = alloc((size_t)N_NODES * 8 * 4);
    size_t o_WbT    = alloc((size_t)9 * 16384 * 2);
    size_t o_xb     = alloc((size_t)N_NODES * D * 2);
    size_t o_xW     = alloc((size_t)N_NODES * 1024 * 2 + 4096);
    if (ws_size < o) return;

    int*            ccnt    = (int*)(ws + o_ccnt);
    int*            coff    = (int*)(ws + o_coff);
    int*            gcur    = (int*)(ws + o_gcur);
    int*            row_off = (int*)(ws + o_rowoff);
    unsigned int*   recA    = (unsigned int*)(ws + o_recA);
    int*            csr     = (int*)(ws + o_csr);
    float*          dinv    = (float*)(ws + o_dinv);
    unsigned short* WbT     = (unsigned short*)(ws + o_WbT);
    unsigned short* xb      = (unsigned short*)(ws + o_xb);
    unsigned short* xW      = (unsigned short*)(ws + o_xW);

    hipMemsetAsync(ccnt, 0, zero_end, stream);

    k_setup1<<<K1_HIST + K1_CVT + K1_MKW, 256, 0, stream>>>(x, coeff, bases, self_loop,
                                                            ei, xb, WbT, ccnt);
    k_scanA1<<<1, 256, 0, stream>>>(ccnt, coff, gcur, row_off);
    k_work<<<391 + 3528, 512, 0, stream>>>(ei, et, gcur, recA, xb, WbT, xW, out, N_NODES);
    k_buildC<<<NCB, 256, 0, stream>>>(recA, coff, row_off, csr, dinv);
    k_gather2<<<12500, 256, 0, stream>>>(xW, csr, row_off, dinv, out);
}